// Round 11
// baseline (113.589 us; speedup 1.0000x reference)
//
#include <hip/hip_runtime.h>

// Problem constants (B=1, L=2048, E=512, H=8, D=64)
constexpr int L_SEQ = 2048;
constexpr int E_DIM = 512;
constexpr int H_NUM = 8;
constexpr int QKV_W = 3 * E_DIM;   // 1536
constexpr int NC = 32;             // 32 chunks of 64
constexpr float PI_HALF = 1.5707963267948966f;

typedef __attribute__((ext_vector_type(8))) short bf16x8;
typedef __attribute__((ext_vector_type(4))) float f32x4;
typedef __attribute__((ext_vector_type(4))) short short4v;

__device__ __forceinline__ short f2bf(float f) {
  union { float f; unsigned int u; } v; v.f = f;
  unsigned int r = v.u + 0x7fffu + ((v.u >> 16) & 1u);  // RNE
  return (short)(r >> 16);
}
__device__ __forceinline__ float bf2f(short s) {
  union { unsigned int u; float f; } v;
  v.u = ((unsigned int)(unsigned short)s) << 16;
  return v.f;
}

__device__ __forceinline__ void glds16(const void* g, void* l) {
  __builtin_amdgcn_global_load_lds(
      (const __attribute__((address_space(1))) unsigned int*)g,
      (__attribute__((address_space(3))) unsigned int*)l, 16, 0, 0);
}

// ---------------------------------------------------------------------------
// bf16 MFMA GEMM: C[M,N] = A[M,K](bf16) @ Bt[N,K](bf16)^T + bias[N]
// BK=128: 4 K-iterations at K=512 (halved barrier drains vs BK=64).
// LDS: gemm1 64x64 -> 32 KB (5 blk/CU by LDS, ~3 by VGPR - occupancy kept).
// OB=true -> C bf16, else C fp32. 256 threads = 4 waves (2x2).
// ---------------------------------------------------------------------------
template <int WTM, int WTN, bool OB>
__global__ __launch_bounds__(256) void gemm_mfma_bf16(
    const short* __restrict__ A, const short* __restrict__ Bt,
    const float* __restrict__ bias, void* __restrict__ Cout,
    int M, int N, int K) {
  constexpr int BM = WTM * 32;
  constexpr int BN = WTN * 32;
  __shared__ short As[BM * 128];  // [r][k], 256 B per row
  __shared__ short Bs[BN * 128];  // [n][k]

  const int t = threadIdx.x;
  const int wave = t >> 6, lane = t & 63, quad = lane >> 4, lr = lane & 15;
  const int row0 = blockIdx.y * BM;
  const int col0 = blockIdx.x * BN;
  const int wrow = (wave >> 1) * (BM / 2);
  const int wcol = (wave & 1) * (BN / 2);

  f32x4 acc[WTM][WTN];
#pragma unroll
  for (int m = 0; m < WTM; ++m)
#pragma unroll
    for (int n = 0; n < WTN; ++n) acc[m][n] = (f32x4){0.f, 0.f, 0.f, 0.f};

  for (int k0 = 0; k0 < K; k0 += 128) {
    // Stage A tile (BM x 128 bf16): 16 lanes/row, 4 rows per wave-pass.
#pragma unroll
    for (int p = wave; p < BM / 4; p += 4) {
      const int idx = p * 64 + lane;
      glds16(A + (size_t)(row0 + (idx >> 4)) * K + k0 + (idx & 15) * 8, As + p * 512);
    }
#pragma unroll
    for (int p = wave; p < BN / 4; p += 4) {
      const int idx = p * 64 + lane;
      glds16(Bt + (size_t)(col0 + (idx >> 4)) * K + k0 + (idx & 15) * 8, Bs + p * 512);
    }
    __syncthreads();

    bf16x8 af[WTM][4], bf_[WTN][4];
#pragma unroll
    for (int m = 0; m < WTM; ++m)
#pragma unroll
      for (int kk = 0; kk < 4; ++kk)
        af[m][kk] = *(const bf16x8*)(As + (wrow + m * 16 + lr) * 128 + kk * 32 + quad * 8);
#pragma unroll
    for (int n = 0; n < WTN; ++n)
#pragma unroll
      for (int kk = 0; kk < 4; ++kk)
        bf_[n][kk] = *(const bf16x8*)(Bs + (wcol + n * 16 + lr) * 128 + kk * 32 + quad * 8);
#pragma unroll
    for (int kk = 0; kk < 4; ++kk)
#pragma unroll
      for (int m = 0; m < WTM; ++m)
#pragma unroll
        for (int n = 0; n < WTN; ++n)
          acc[m][n] = __builtin_amdgcn_mfma_f32_16x16x32_bf16(af[m][kk], bf_[n][kk], acc[m][n], 0, 0, 0);
    __syncthreads();
  }

#pragma unroll
  for (int m = 0; m < WTM; ++m) {
#pragma unroll
    for (int n = 0; n < WTN; ++n) {
      const int col = col0 + wcol + n * 16 + lr;
      const int rowb = row0 + wrow + m * 16 + quad * 4;
      const float bb = bias[col];
#pragma unroll
      for (int r = 0; r < 4; ++r) {
        const float val = acc[m][n][r] + bb;
        if (OB)
          ((short*)Cout)[(size_t)(rowb + r) * N + col] = f2bf(val);
        else
          ((float*)Cout)[(size_t)(rowb + r) * N + col] = val;
      }
    }
  }
}

// ---------------------------------------------------------------------------
// Fused prep: cast x -> bf16; transpose-cast W_qkv, W_out -> [N,K] bf16.
// ---------------------------------------------------------------------------
__global__ __launch_bounds__(256) void prep_kernel(
    const float* __restrict__ x, const float* __restrict__ W_qkv,
    const float* __restrict__ W_out, short* __restrict__ xb,
    short* __restrict__ Wqkv_t, short* __restrict__ Wout_t) {
  const int b = blockIdx.x;
  if (b < 1024) {
    const int i = b * 256 + threadIdx.x;
    const float4 v = ((const float4*)x)[i];
    short4v o;
    o.x = f2bf(v.x); o.y = f2bf(v.y); o.z = f2bf(v.z); o.w = f2bf(v.w);
    ((short4v*)xb)[i] = o;
    return;
  }
  __shared__ float tile[32][33];
  const float* W; short* Wt; int Cc, c0, r0;
  if (b < 1792) {
    const int bb = b - 1024;
    W = W_qkv; Wt = Wqkv_t; Cc = QKV_W;
    c0 = (bb % 48) * 32; r0 = (bb / 48) * 32;
  } else {
    const int bb = b - 1792;
    W = W_out; Wt = Wout_t; Cc = E_DIM;
    c0 = (bb % 16) * 32; r0 = (bb / 16) * 32;
  }
  const int tx = threadIdx.x & 31, ty = threadIdx.x >> 5;
  for (int i = ty; i < 32; i += 8) tile[i][tx] = W[(size_t)(r0 + i) * Cc + c0 + tx];
  __syncthreads();
  for (int i = ty; i < 32; i += 8)
    Wt[(size_t)(c0 + i) * E_DIM + r0 + tx] = f2bf(tile[tx][i]);
}

// ---------------------------------------------------------------------------
// Kernel A (MFMA), grid (NC, H, 2): half = cos(0)/sin(1) split -> 512 blocks.
//   S[(h,c)][e][64*half + dd'] = sum_i v[i][e] * kw_half[i][dd']
//   ksum[(h,c)][64*half + dd'] = sum_i kw_half[i][dd']
// ---------------------------------------------------------------------------
__global__ __launch_bounds__(256) void chunk_kv_half(
    const short* __restrict__ qkvb, short* __restrict__ Sb, float* __restrict__ ksum) {
  const int c = blockIdx.x, h = blockIdx.y, half = blockIdx.z;
  __shared__ short kT[64][72];  // kw^T [dd'][i] (this half's weighting)
  __shared__ short vT[64][72];  // v^T  [e][i]
  const int t = threadIdx.x;
  const int wave = t >> 6, lane = t & 63, quad = lane >> 4, lr = lane & 15;

#pragma unroll
  for (int r = 0; r < 2; ++r) {
    const int idx = r * 256 + t;
    const int i = idx >> 3, dg = idx & 7;
    const short* row = qkvb + (size_t)(c * 64 + i) * QKV_W + h * 64 + dg * 8;
    const bf16x8 kb = *(const bf16x8*)(row + E_DIM);
    const bf16x8 vb = *(const bf16x8*)(row + 2 * E_DIM);
    float sw, cw;
    __sincosf(PI_HALF * (float)(c * 64 + i) / (float)L_SEQ, &sw, &cw);
    const float wgt = half ? sw : cw;
#pragma unroll
    for (int q = 0; q < 8; ++q) {
      kT[dg * 8 + q][i] = f2bf(fmaxf(bf2f(kb[q]), 0.f) * wgt);
      vT[dg * 8 + q][i] = vb[q];
    }
  }
  __syncthreads();

  f32x4 sacc[4];
#pragma unroll
  for (int n = 0; n < 4; ++n) sacc[n] = (f32x4){0.f, 0.f, 0.f, 0.f};
#pragma unroll
  for (int kk = 0; kk < 2; ++kk) {
    const bf16x8 av = *(const bf16x8*)&vT[16 * wave + lr][kk * 32 + quad * 8];
#pragma unroll
    for (int n = 0; n < 4; ++n) {
      const bf16x8 bv = *(const bf16x8*)&kT[16 * n + lr][kk * 32 + quad * 8];
      sacc[n] = __builtin_amdgcn_mfma_f32_16x16x32_bf16(av, bv, sacc[n], 0, 0, 0);
    }
  }
  short* Sc = Sb + ((size_t)(h * NC + c)) * 8192;  // [e][128]
#pragma unroll
  for (int n = 0; n < 4; ++n) {
    const int dd = 64 * half + 16 * n + lr;
#pragma unroll
    for (int r = 0; r < 4; ++r) {
      const int e = 16 * wave + quad * 4 + r;
      Sc[(size_t)e * 128 + dd] = f2bf(sacc[n][r]);
    }
  }
  if (t < 64) {
    float s = 0.f;
#pragma unroll
    for (int j = 0; j < 8; ++j) {
      const bf16x8 kv8 = *(const bf16x8*)&kT[t][j * 8];
#pragma unroll
      for (int q = 0; q < 8; ++q) s += bf2f(kv8[q]);
    }
    ksum[(size_t)(h * NC + c) * 128 + 64 * half + t] = s;
  }
}

// ---------------------------------------------------------------------------
// Kernel B: balanced exclusive prefix scan (bf16 Sp out, fp32 ksumP).
// ---------------------------------------------------------------------------
__global__ __launch_bounds__(256) void scan_kernel(
    const short* __restrict__ Sb, short* __restrict__ Spb,
    const float* __restrict__ ksum, float* __restrict__ ksumP) {
  const int h = blockIdx.y;
  const int g = (blockIdx.x * 256 + threadIdx.x) * 8;
  float run[8];
#pragma unroll
  for (int q = 0; q < 8; ++q) run[q] = 0.f;
#pragma unroll
  for (int c = 0; c < NC; ++c) {
    const size_t off = ((size_t)(h * NC + c)) * 8192 + g;
    const bf16x8 v8 = *(const bf16x8*)(Sb + off);
    bf16x8 o;
#pragma unroll
    for (int q = 0; q < 8; ++q) o[q] = f2bf(run[q]);
    *(bf16x8*)(Spb + off) = o;
#pragma unroll
    for (int q = 0; q < 8; ++q) run[q] += bf2f(v8[q]);
  }
  if (blockIdx.x == 0 && threadIdx.x < 128) {
    const int d = threadIdx.x;
    float r2 = 0.f;
#pragma unroll
    for (int c = 0; c < NC; ++c) {
      const size_t off = (size_t)(h * NC + c) * 128 + d;
      ksumP[off] = r2;
      r2 += ksum[off];
    }
  }
}

// ---------------------------------------------------------------------------
// Kernel C (MFMA), grid (NC, H, 2): half = e-half split -> 512 blocks.
//   ctx[.,e-half] = Qc @ Spb^T (global B-frags) + Am @ vT^T
//   nrm = rowsum(Am) + Qc . ksumP  (full, duplicated across halves)
// ---------------------------------------------------------------------------
__global__ __launch_bounds__(256) void chunk_out_half(
    const short* __restrict__ qkvb, const short* __restrict__ Spb,
    const float* __restrict__ ksumP, short* __restrict__ attn) {
  const int c = blockIdx.x, h = blockIdx.y, eh = blockIdx.z;
  __shared__ short Qc[64][136];
  __shared__ short Kc[64][136];
  __shared__ short Am[64][72];
  __shared__ short vT[32][72];   // own 32-e half, transposed
  __shared__ float nrmP[64][4];
  __shared__ float nrmA[64];
  const int t = threadIdx.x;
  const int wave = t >> 6, lane = t & 63, quad = lane >> 4, lr = lane & 15;

#pragma unroll
  for (int r = 0; r < 2; ++r) {
    const int idx = r * 256 + t;
    const int i = idx >> 3, dg = idx & 7;
    const short* row = qkvb + (size_t)(c * 64 + i) * QKV_W + h * 64 + dg * 8;
    const bf16x8 qb = *(const bf16x8*)row;
    const bf16x8 kb = *(const bf16x8*)(row + E_DIM);
    float sw, cw;
    __sincosf(PI_HALF * (float)(c * 64 + i) / (float)L_SEQ, &sw, &cw);
    bf16x8 qc, qs, kc, ks;
#pragma unroll
    for (int q = 0; q < 8; ++q) {
      const float qv = fmaxf(bf2f(qb[q]), 0.f);
      const float kv = fmaxf(bf2f(kb[q]), 0.f);
      qc[q] = f2bf(qv * cw); qs[q] = f2bf(qv * sw);
      kc[q] = f2bf(kv * cw); ks[q] = f2bf(kv * sw);
    }
    *(bf16x8*)&Qc[i][dg * 8] = qc;
    *(bf16x8*)&Qc[i][64 + dg * 8] = qs;
    *(bf16x8*)&Kc[i][dg * 8] = kc;
    *(bf16x8*)&Kc[i][64 + dg * 8] = ks;
  }
  {
    const int i = t >> 2, dg = (t & 3) + 4 * eh;
    const bf16x8 vb = *(const bf16x8*)(qkvb + (size_t)(c * 64 + i) * QKV_W +
                                       2 * E_DIM + h * 64 + dg * 8);
    const int el0 = (dg - 4 * eh) * 8;
#pragma unroll
    for (int q = 0; q < 8; ++q) vT[el0 + q][i] = vb[q];
  }
  __syncthreads();

  bf16x8 av[4];
#pragma unroll
  for (int kk = 0; kk < 4; ++kk)
    av[kk] = *(const bf16x8*)&Qc[16 * wave + lr][kk * 32 + quad * 8];

  f32x4 acc_a[4];
#pragma unroll
  for (int n = 0; n < 4; ++n) acc_a[n] = (f32x4){0.f, 0.f, 0.f, 0.f};
#pragma unroll
  for (int kk = 0; kk < 4; ++kk) {
#pragma unroll
    for (int n = 0; n < 4; ++n) {
      const bf16x8 bv = *(const bf16x8*)&Kc[16 * n + lr][kk * 32 + quad * 8];
      acc_a[n] = __builtin_amdgcn_mfma_f32_16x16x32_bf16(av[kk], bv, acc_a[n], 0, 0, 0);
    }
  }
#pragma unroll
  for (int n = 0; n < 4; ++n) {
#pragma unroll
    for (int r = 0; r < 4; ++r) {
      const int gi = 16 * wave + quad * 4 + r;
      const int gj = 16 * n + lr;
      float val = (gj <= gi) ? acc_a[n][r] : 0.f;
      Am[gi][gj] = f2bf(val);
      float s = val;
      s += __shfl_xor(s, 1, 64);
      s += __shfl_xor(s, 2, 64);
      s += __shfl_xor(s, 4, 64);
      s += __shfl_xor(s, 8, 64);
      if (lr == 0) nrmP[gi][n] = s;
    }
  }

  const short* Spc = Spb + ((size_t)(h * NC + c)) * 8192;  // [e][128]
  f32x4 acc_c[2];
#pragma unroll
  for (int n = 0; n < 2; ++n) acc_c[n] = (f32x4){0.f, 0.f, 0.f, 0.f};
#pragma unroll
  for (int kk = 0; kk < 4; ++kk) {
#pragma unroll
    for (int n2 = 0; n2 < 2; ++n2) {
      const int e = 32 * eh + 16 * n2 + lr;
      const bf16x8 bv = *(const bf16x8*)(Spc + (size_t)e * 128 + kk * 32 + quad * 8);
      acc_c[n2] = __builtin_amdgcn_mfma_f32_16x16x32_bf16(av[kk], bv, acc_c[n2], 0, 0, 0);
    }
  }
  __syncthreads();  // Am, nrmP ready

#pragma unroll
  for (int kk = 0; kk < 2; ++kk) {
    const bf16x8 am = *(const bf16x8*)&Am[16 * wave + lr][kk * 32 + quad * 8];
#pragma unroll
    for (int n2 = 0; n2 < 2; ++n2) {
      const bf16x8 bv = *(const bf16x8*)&vT[16 * n2 + lr][kk * 32 + quad * 8];
      acc_c[n2] = __builtin_amdgcn_mfma_f32_16x16x32_bf16(am, bv, acc_c[n2], 0, 0, 0);
    }
  }

  {
    const int i = t >> 2, p = t & 3;
    const float* Kp = ksumP + (size_t)(h * NC + c) * 128;
    float dot = 0.f;
#pragma unroll
    for (int jj = 0; jj < 32; ++jj) {
      const int dd = p * 32 + jj;
      dot += bf2f(Qc[i][dd]) * Kp[dd];
    }
    nrmP[i][p] += dot;
  }
  __syncthreads();
  if (t < 64) nrmA[t] = nrmP[t][0] + nrmP[t][1] + nrmP[t][2] + nrmP[t][3];
  __syncthreads();

#pragma unroll
  for (int n2 = 0; n2 < 2; ++n2) {
#pragma unroll
    for (int r = 0; r < 4; ++r) {
      const int gi = 16 * wave + quad * 4 + r;
      const int e = 32 * eh + 16 * n2 + lr;
      const float val = acc_c[n2][r] / (nrmA[gi] + 1e-6f);
      attn[(size_t)(c * 64 + gi) * E_DIM + h * 64 + e] = f2bf(val);
    }
  }
}

// ---------------------------------------------------------------------------
extern "C" void kernel_launch(void* const* d_in, const int* in_sizes, int n_in,
                              void* d_out, int out_size, void* d_ws, size_t ws_size,
                              hipStream_t stream) {
  (void)in_sizes; (void)n_in; (void)out_size; (void)ws_size;
  const float* x     = (const float*)d_in[0];
  const float* W_qkv = (const float*)d_in[1];
  const float* b_qkv = (const float*)d_in[2];
  const float* W_out = (const float*)d_in[3];
  const float* b_out = (const float*)d_in[4];
  float* out = (float*)d_out;

  short* sws = (short*)d_ws;
  short* qkvb   = sws;                     // 3,145,728 bf16
  short* Sb     = qkvb + 3145728;          // 2,097,152 bf16  [hc][e][dd]
  short* Spb    = Sb + 2097152;            // 2,097,152 bf16
  short* attn_b = Spb + 2097152;           // 1,048,576 bf16
  short* xb     = attn_b + 1048576;        // 1,048,576 bf16
  short* Wqkv_t = xb + 1048576;            // 786,432 bf16
  short* Wout_t = Wqkv_t + 786432;         // 262,144 bf16
  float* ksum   = (float*)(Wout_t + 262144);  // 32,768 f32
  float* ksumP  = ksum + 32768;               // 32,768 f32

  // 1) fused prep
  prep_kernel<<<2048, 256, 0, stream>>>(x, W_qkv, W_out, xb, Wqkv_t, Wout_t);

  // 2) qkv = x @ W_qkv + b_qkv -> bf16. 64x64 tiles, BK=128: 768 blocks (3/CU)
  gemm_mfma_bf16<2, 2, true><<<dim3(QKV_W / 64, L_SEQ / 64), 256, 0, stream>>>(
      xb, Wqkv_t, b_qkv, qkvb, L_SEQ, QKV_W, E_DIM);

  // 3) per-chunk KV sums, cos/sin split -> 512 blocks
  chunk_kv_half<<<dim3(NC, H_NUM, 2), 256, 0, stream>>>(qkvb, Sb, ksum);

  // 4) balanced exclusive prefix scan -> bf16 Sp, fp32 ksumP
  scan_kernel<<<dim3(4, H_NUM), 256, 0, stream>>>(Sb, Spb, ksum, ksumP);

  // 5) per-chunk outputs, e-half split -> 512 blocks
  chunk_out_half<<<dim3(NC, H_NUM, 2), 256, 0, stream>>>(qkvb, Spb, ksumP, attn_b);

  // 6) out = attn @ W_out + b_out -> fp32. 32x64 tiles, BK=128: 512 blocks
  gemm_mfma_bf16<1, 2, false><<<dim3(E_DIM / 64, L_SEQ / 32), 256, 0, stream>>>(
      attn_b, Wout_t, b_out, out, L_SEQ, E_DIM, E_DIM);
}

// Round 12
// 106.699 us; speedup vs baseline: 1.0646x; 1.0646x over previous
//
#include <hip/hip_runtime.h>

// Problem constants (B=1, L=2048, E=512, H=8, D=64)
constexpr int L_SEQ = 2048;
constexpr int E_DIM = 512;
constexpr int H_NUM = 8;
constexpr int QKV_W = 3 * E_DIM;   // 1536
constexpr int NC = 32;             // 32 chunks of 64
constexpr float PI_HALF = 1.5707963267948966f;

typedef __attribute__((ext_vector_type(8))) short bf16x8;
typedef __attribute__((ext_vector_type(4))) float f32x4;
typedef __attribute__((ext_vector_type(4))) short short4v;

__device__ __forceinline__ short f2bf(float f) {
  union { float f; unsigned int u; } v; v.f = f;
  unsigned int r = v.u + 0x7fffu + ((v.u >> 16) & 1u);  // RNE
  return (short)(r >> 16);
}
__device__ __forceinline__ float bf2f(short s) {
  union { unsigned int u; float f; } v;
  v.u = ((unsigned int)(unsigned short)s) << 16;
  return v.f;
}

__device__ __forceinline__ void glds16(const void* g, void* l) {
  __builtin_amdgcn_global_load_lds(
      (const __attribute__((address_space(1))) unsigned int*)g,
      (__attribute__((address_space(3))) unsigned int*)l, 16, 0, 0);
}

// ---------------------------------------------------------------------------
// bf16 MFMA GEMM: C[M,N] = A[M,K](bf16) @ Bt[N,K](bf16)^T + bias[N]
// BK=64 (measured optimum r10/r11: BK=128 VGPR-cliffs, BK=32 barrier-heavy).
// OB=true -> C bf16, else C fp32. 256 threads = 4 waves (2x2).
// ---------------------------------------------------------------------------
template <int WTM, int WTN, bool OB>
__global__ __launch_bounds__(256) void gemm_mfma_bf16(
    const short* __restrict__ A, const short* __restrict__ Bt,
    const float* __restrict__ bias, void* __restrict__ Cout,
    int M, int N, int K) {
  constexpr int BM = WTM * 32;
  constexpr int BN = WTN * 32;
  __shared__ short As[BM * 64];  // [r][k], 128 B per row
  __shared__ short Bs[BN * 64];  // [n][k]

  const int t = threadIdx.x;
  const int wave = t >> 6, lane = t & 63, quad = lane >> 4, lr = lane & 15;
  const int row0 = blockIdx.y * BM;
  const int col0 = blockIdx.x * BN;
  const int wrow = (wave >> 1) * (BM / 2);
  const int wcol = (wave & 1) * (BN / 2);

  f32x4 acc[WTM][WTN];
#pragma unroll
  for (int m = 0; m < WTM; ++m)
#pragma unroll
    for (int n = 0; n < WTN; ++n) acc[m][n] = (f32x4){0.f, 0.f, 0.f, 0.f};

  for (int k0 = 0; k0 < K; k0 += 64) {
    // Stage A tile (BM x 64 bf16): each wave-pass covers 8 rows (1024 B).
#pragma unroll
    for (int p = wave; p < BM / 8; p += 4) {
      const int idx = p * 64 + lane;
      glds16(A + (size_t)(row0 + (idx >> 3)) * K + k0 + (idx & 7) * 8, As + p * 512);
    }
#pragma unroll
    for (int p = wave; p < BN / 8; p += 4) {
      const int idx = p * 64 + lane;
      glds16(Bt + (size_t)(col0 + (idx >> 3)) * K + k0 + (idx & 7) * 8, Bs + p * 512);
    }
    __syncthreads();

    bf16x8 af[WTM][2], bf_[WTN][2];
#pragma unroll
    for (int m = 0; m < WTM; ++m)
#pragma unroll
      for (int kk = 0; kk < 2; ++kk)
        af[m][kk] = *(const bf16x8*)(As + (wrow + m * 16 + lr) * 64 + kk * 32 + quad * 8);
#pragma unroll
    for (int n = 0; n < WTN; ++n)
#pragma unroll
      for (int kk = 0; kk < 2; ++kk)
        bf_[n][kk] = *(const bf16x8*)(Bs + (wcol + n * 16 + lr) * 64 + kk * 32 + quad * 8);
#pragma unroll
    for (int kk = 0; kk < 2; ++kk)
#pragma unroll
      for (int m = 0; m < WTM; ++m)
#pragma unroll
        for (int n = 0; n < WTN; ++n)
          acc[m][n] = __builtin_amdgcn_mfma_f32_16x16x32_bf16(af[m][kk], bf_[n][kk], acc[m][n], 0, 0, 0);
    __syncthreads();
  }

#pragma unroll
  for (int m = 0; m < WTM; ++m) {
#pragma unroll
    for (int n = 0; n < WTN; ++n) {
      const int col = col0 + wcol + n * 16 + lr;
      const int rowb = row0 + wrow + m * 16 + quad * 4;
      const float bb = bias[col];
#pragma unroll
      for (int r = 0; r < 4; ++r) {
        const float val = acc[m][n][r] + bb;
        if (OB)
          ((short*)Cout)[(size_t)(rowb + r) * N + col] = f2bf(val);
        else
          ((float*)Cout)[(size_t)(rowb + r) * N + col] = val;
      }
    }
  }
}

// ---------------------------------------------------------------------------
// Fused prep: cast x -> bf16; transpose-cast W_qkv, W_out -> [N,K] bf16.
// ---------------------------------------------------------------------------
__global__ __launch_bounds__(256) void prep_kernel(
    const float* __restrict__ x, const float* __restrict__ W_qkv,
    const float* __restrict__ W_out, short* __restrict__ xb,
    short* __restrict__ Wqkv_t, short* __restrict__ Wout_t) {
  const int b = blockIdx.x;
  if (b < 1024) {
    const int i = b * 256 + threadIdx.x;
    const float4 v = ((const float4*)x)[i];
    short4v o;
    o.x = f2bf(v.x); o.y = f2bf(v.y); o.z = f2bf(v.z); o.w = f2bf(v.w);
    ((short4v*)xb)[i] = o;
    return;
  }
  __shared__ float tile[32][33];
  const float* W; short* Wt; int Cc, c0, r0;
  if (b < 1792) {
    const int bb = b - 1024;
    W = W_qkv; Wt = Wqkv_t; Cc = QKV_W;
    c0 = (bb % 48) * 32; r0 = (bb / 48) * 32;
  } else {
    const int bb = b - 1792;
    W = W_out; Wt = Wout_t; Cc = E_DIM;
    c0 = (bb % 16) * 32; r0 = (bb / 16) * 32;
  }
  const int tx = threadIdx.x & 31, ty = threadIdx.x >> 5;
  for (int i = ty; i < 32; i += 8) tile[i][tx] = W[(size_t)(r0 + i) * Cc + c0 + tx];
  __syncthreads();
  for (int i = ty; i < 32; i += 8)
    Wt[(size_t)(c0 + i) * E_DIM + r0 + tx] = f2bf(tile[tx][i]);
}

// ---------------------------------------------------------------------------
// Kernel A (MFMA), grid (NC, H, 2): half = cos(0)/sin(1) split -> 512 blocks.
//   S[(h,c)][e][64*half + dd'] = sum_i v[i][e] * kw_half[i][dd']
//   ksum[(h,c)][64*half + dd'] = sum_i kw_half[i][dd']
// ---------------------------------------------------------------------------
__global__ __launch_bounds__(256) void chunk_kv_half(
    const short* __restrict__ qkvb, short* __restrict__ Sb, float* __restrict__ ksum) {
  const int c = blockIdx.x, h = blockIdx.y, half = blockIdx.z;
  __shared__ short kT[64][72];  // kw^T [dd'][i] (this half's weighting)
  __shared__ short vT[64][72];  // v^T  [e][i]
  const int t = threadIdx.x;
  const int wave = t >> 6, lane = t & 63, quad = lane >> 4, lr = lane & 15;

#pragma unroll
  for (int r = 0; r < 2; ++r) {
    const int idx = r * 256 + t;
    const int i = idx >> 3, dg = idx & 7;
    const short* row = qkvb + (size_t)(c * 64 + i) * QKV_W + h * 64 + dg * 8;
    const bf16x8 kb = *(const bf16x8*)(row + E_DIM);
    const bf16x8 vb = *(const bf16x8*)(row + 2 * E_DIM);
    float sw, cw;
    __sincosf(PI_HALF * (float)(c * 64 + i) / (float)L_SEQ, &sw, &cw);
    const float wgt = half ? sw : cw;
#pragma unroll
    for (int q = 0; q < 8; ++q) {
      kT[dg * 8 + q][i] = f2bf(fmaxf(bf2f(kb[q]), 0.f) * wgt);
      vT[dg * 8 + q][i] = vb[q];
    }
  }
  __syncthreads();

  f32x4 sacc[4];
#pragma unroll
  for (int n = 0; n < 4; ++n) sacc[n] = (f32x4){0.f, 0.f, 0.f, 0.f};
#pragma unroll
  for (int kk = 0; kk < 2; ++kk) {
    const bf16x8 av = *(const bf16x8*)&vT[16 * wave + lr][kk * 32 + quad * 8];
#pragma unroll
    for (int n = 0; n < 4; ++n) {
      const bf16x8 bv = *(const bf16x8*)&kT[16 * n + lr][kk * 32 + quad * 8];
      sacc[n] = __builtin_amdgcn_mfma_f32_16x16x32_bf16(av, bv, sacc[n], 0, 0, 0);
    }
  }
  short* Sc = Sb + ((size_t)(h * NC + c)) * 8192;  // [e][128]
#pragma unroll
  for (int n = 0; n < 4; ++n) {
    const int dd = 64 * half + 16 * n + lr;
#pragma unroll
    for (int r = 0; r < 4; ++r) {
      const int e = 16 * wave + quad * 4 + r;
      Sc[(size_t)e * 128 + dd] = f2bf(sacc[n][r]);
    }
  }
  if (t < 64) {
    float s = 0.f;
#pragma unroll
    for (int j = 0; j < 8; ++j) {
      const bf16x8 kv8 = *(const bf16x8*)&kT[t][j * 8];
#pragma unroll
      for (int q = 0; q < 8; ++q) s += bf2f(kv8[q]);
    }
    ksum[(size_t)(h * NC + c) * 128 + 64 * half + t] = s;
  }
}

// ---------------------------------------------------------------------------
// Kernel B: balanced exclusive prefix scan (bf16 Sp out, fp32 ksumP).
// ---------------------------------------------------------------------------
__global__ __launch_bounds__(256) void scan_kernel(
    const short* __restrict__ Sb, short* __restrict__ Spb,
    const float* __restrict__ ksum, float* __restrict__ ksumP) {
  const int h = blockIdx.y;
  const int g = (blockIdx.x * 256 + threadIdx.x) * 8;
  float run[8];
#pragma unroll
  for (int q = 0; q < 8; ++q) run[q] = 0.f;
#pragma unroll
  for (int c = 0; c < NC; ++c) {
    const size_t off = ((size_t)(h * NC + c)) * 8192 + g;
    const bf16x8 v8 = *(const bf16x8*)(Sb + off);
    bf16x8 o;
#pragma unroll
    for (int q = 0; q < 8; ++q) o[q] = f2bf(run[q]);
    *(bf16x8*)(Spb + off) = o;
#pragma unroll
    for (int q = 0; q < 8; ++q) run[q] += bf2f(v8[q]);
  }
  if (blockIdx.x == 0 && threadIdx.x < 128) {
    const int d = threadIdx.x;
    float r2 = 0.f;
#pragma unroll
    for (int c = 0; c < NC; ++c) {
      const size_t off = (size_t)(h * NC + c) * 128 + d;
      ksumP[off] = r2;
      r2 += ksum[off];
    }
  }
}

// ---------------------------------------------------------------------------
// Kernel C (MFMA), grid (NC, H, 2): half = e-half split -> 512 blocks.
//   ctx[.,e-half] = Qc @ Spb^T (global B-frags) + Am @ vT^T
//   nrm = rowsum(Am) + Qc . ksumP  (full, duplicated across halves)
// ---------------------------------------------------------------------------
__global__ __launch_bounds__(256) void chunk_out_half(
    const short* __restrict__ qkvb, const short* __restrict__ Spb,
    const float* __restrict__ ksumP, short* __restrict__ attn) {
  const int c = blockIdx.x, h = blockIdx.y, eh = blockIdx.z;
  __shared__ short Qc[64][136];
  __shared__ short Kc[64][136];
  __shared__ short Am[64][72];
  __shared__ short vT[32][72];   // own 32-e half, transposed
  __shared__ float nrmP[64][4];
  __shared__ float nrmA[64];
  const int t = threadIdx.x;
  const int wave = t >> 6, lane = t & 63, quad = lane >> 4, lr = lane & 15;

#pragma unroll
  for (int r = 0; r < 2; ++r) {
    const int idx = r * 256 + t;
    const int i = idx >> 3, dg = idx & 7;
    const short* row = qkvb + (size_t)(c * 64 + i) * QKV_W + h * 64 + dg * 8;
    const bf16x8 qb = *(const bf16x8*)row;
    const bf16x8 kb = *(const bf16x8*)(row + E_DIM);
    float sw, cw;
    __sincosf(PI_HALF * (float)(c * 64 + i) / (float)L_SEQ, &sw, &cw);
    bf16x8 qc, qs, kc, ks;
#pragma unroll
    for (int q = 0; q < 8; ++q) {
      const float qv = fmaxf(bf2f(qb[q]), 0.f);
      const float kv = fmaxf(bf2f(kb[q]), 0.f);
      qc[q] = f2bf(qv * cw); qs[q] = f2bf(qv * sw);
      kc[q] = f2bf(kv * cw); ks[q] = f2bf(kv * sw);
    }
    *(bf16x8*)&Qc[i][dg * 8] = qc;
    *(bf16x8*)&Qc[i][64 + dg * 8] = qs;
    *(bf16x8*)&Kc[i][dg * 8] = kc;
    *(bf16x8*)&Kc[i][64 + dg * 8] = ks;
  }
  {
    const int i = t >> 2, dg = (t & 3) + 4 * eh;
    const bf16x8 vb = *(const bf16x8*)(qkvb + (size_t)(c * 64 + i) * QKV_W +
                                       2 * E_DIM + h * 64 + dg * 8);
    const int el0 = (dg - 4 * eh) * 8;
#pragma unroll
    for (int q = 0; q < 8; ++q) vT[el0 + q][i] = vb[q];
  }
  __syncthreads();

  bf16x8 av[4];
#pragma unroll
  for (int kk = 0; kk < 4; ++kk)
    av[kk] = *(const bf16x8*)&Qc[16 * wave + lr][kk * 32 + quad * 8];

  f32x4 acc_a[4];
#pragma unroll
  for (int n = 0; n < 4; ++n) acc_a[n] = (f32x4){0.f, 0.f, 0.f, 0.f};
#pragma unroll
  for (int kk = 0; kk < 4; ++kk) {
#pragma unroll
    for (int n = 0; n < 4; ++n) {
      const bf16x8 bv = *(const bf16x8*)&Kc[16 * n + lr][kk * 32 + quad * 8];
      acc_a[n] = __builtin_amdgcn_mfma_f32_16x16x32_bf16(av[kk], bv, acc_a[n], 0, 0, 0);
    }
  }
#pragma unroll
  for (int n = 0; n < 4; ++n) {
#pragma unroll
    for (int r = 0; r < 4; ++r) {
      const int gi = 16 * wave + quad * 4 + r;
      const int gj = 16 * n + lr;
      float val = (gj <= gi) ? acc_a[n][r] : 0.f;
      Am[gi][gj] = f2bf(val);
      float s = val;
      s += __shfl_xor(s, 1, 64);
      s += __shfl_xor(s, 2, 64);
      s += __shfl_xor(s, 4, 64);
      s += __shfl_xor(s, 8, 64);
      if (lr == 0) nrmP[gi][n] = s;
    }
  }

  const short* Spc = Spb + ((size_t)(h * NC + c)) * 8192;  // [e][128]
  f32x4 acc_c[2];
#pragma unroll
  for (int n = 0; n < 2; ++n) acc_c[n] = (f32x4){0.f, 0.f, 0.f, 0.f};
#pragma unroll
  for (int kk = 0; kk < 4; ++kk) {
#pragma unroll
    for (int n2 = 0; n2 < 2; ++n2) {
      const int e = 32 * eh + 16 * n2 + lr;
      const bf16x8 bv = *(const bf16x8*)(Spc + (size_t)e * 128 + kk * 32 + quad * 8);
      acc_c[n2] = __builtin_amdgcn_mfma_f32_16x16x32_bf16(av[kk], bv, acc_c[n2], 0, 0, 0);
    }
  }
  __syncthreads();  // Am, nrmP ready

#pragma unroll
  for (int kk = 0; kk < 2; ++kk) {
    const bf16x8 am = *(const bf16x8*)&Am[16 * wave + lr][kk * 32 + quad * 8];
#pragma unroll
    for (int n2 = 0; n2 < 2; ++n2) {
      const bf16x8 bv = *(const bf16x8*)&vT[16 * n2 + lr][kk * 32 + quad * 8];
      acc_c[n2] = __builtin_amdgcn_mfma_f32_16x16x32_bf16(am, bv, acc_c[n2], 0, 0, 0);
    }
  }

  {
    const int i = t >> 2, p = t & 3;
    const float* Kp = ksumP + (size_t)(h * NC + c) * 128;
    float dot = 0.f;
#pragma unroll
    for (int jj = 0; jj < 32; ++jj) {
      const int dd = p * 32 + jj;
      dot += bf2f(Qc[i][dd]) * Kp[dd];
    }
    nrmP[i][p] += dot;
  }
  __syncthreads();
  if (t < 64) nrmA[t] = nrmP[t][0] + nrmP[t][1] + nrmP[t][2] + nrmP[t][3];
  __syncthreads();

#pragma unroll
  for (int n2 = 0; n2 < 2; ++n2) {
#pragma unroll
    for (int r = 0; r < 4; ++r) {
      const int gi = 16 * wave + quad * 4 + r;
      const int e = 32 * eh + 16 * n2 + lr;
      const float val = acc_c[n2][r] / (nrmA[gi] + 1e-6f);
      attn[(size_t)(c * 64 + gi) * E_DIM + h * 64 + e] = f2bf(val);
    }
  }
}

// ---------------------------------------------------------------------------
extern "C" void kernel_launch(void* const* d_in, const int* in_sizes, int n_in,
                              void* d_out, int out_size, void* d_ws, size_t ws_size,
                              hipStream_t stream) {
  (void)in_sizes; (void)n_in; (void)out_size; (void)ws_size;
  const float* x     = (const float*)d_in[0];
  const float* W_qkv = (const float*)d_in[1];
  const float* b_qkv = (const float*)d_in[2];
  const float* W_out = (const float*)d_in[3];
  const float* b_out = (const float*)d_in[4];
  float* out = (float*)d_out;

  short* sws = (short*)d_ws;
  short* qkvb   = sws;                     // 3,145,728 bf16
  short* Sb     = qkvb + 3145728;          // 2,097,152 bf16  [hc][e][dd]
  short* Spb    = Sb + 2097152;            // 2,097,152 bf16
  short* attn_b = Spb + 2097152;           // 1,048,576 bf16
  short* xb     = attn_b + 1048576;        // 1,048,576 bf16
  short* Wqkv_t = xb + 1048576;            // 786,432 bf16
  short* Wout_t = Wqkv_t + 786432;         // 262,144 bf16
  float* ksum   = (float*)(Wout_t + 262144);  // 32,768 f32
  float* ksumP  = ksum + 32768;               // 32,768 f32

  // 1) fused prep
  prep_kernel<<<2048, 256, 0, stream>>>(x, W_qkv, W_out, xb, Wqkv_t, Wout_t);

  // 2) qkv = x @ W_qkv + b_qkv -> bf16. 64x96 tiles, BK=64: 16x32 = 512 blocks (2/CU, balanced)
  gemm_mfma_bf16<2, 3, true><<<dim3(QKV_W / 96, L_SEQ / 64), 256, 0, stream>>>(
      xb, Wqkv_t, b_qkv, qkvb, L_SEQ, QKV_W, E_DIM);

  // 3) per-chunk KV sums, cos/sin split -> 512 blocks
  chunk_kv_half<<<dim3(NC, H_NUM, 2), 256, 0, stream>>>(qkvb, Sb, ksum);

  // 4) balanced exclusive prefix scan -> bf16 Sp, fp32 ksumP
  scan_kernel<<<dim3(4, H_NUM), 256, 0, stream>>>(Sb, Spb, ksum, ksumP);

  // 5) per-chunk outputs, e-half split -> 512 blocks
  chunk_out_half<<<dim3(NC, H_NUM, 2), 256, 0, stream>>>(qkvb, Spb, ksumP, attn_b);

  // 6) out = attn @ W_out + b_out -> fp32. 32x64 tiles, BK=64: 512 blocks
  gemm_mfma_bf16<1, 2, false><<<dim3(E_DIM / 64, L_SEQ / 32), 256, 0, stream>>>(
      attn_b, Wout_t, b_out, out, L_SEQ, E_DIM, E_DIM);
}